// Round 2
// baseline (469.511 us; speedup 1.0000x reference)
//
#include <hip/hip_runtime.h>

// Window MHA: B=16, H=W=64, C=512, WS=8, NH=16, hd=32.
// Device buffers are FLOAT32 (reference dtype). Internals use bf16 MFMA with
// f32 accumulate; qkv/attn scratch stored bf16 in d_ws.

typedef unsigned short u16;
typedef unsigned int u32;
typedef __attribute__((ext_vector_type(8))) u16 u16x8;
typedef __attribute__((ext_vector_type(8))) short short8;
typedef __attribute__((ext_vector_type(4))) float f32x4;

__device__ __forceinline__ float bf2f(u16 u) {
    return __uint_as_float(((u32)u) << 16);
}
__device__ __forceinline__ u16 f2bf(float f) {
    u32 u = __float_as_uint(f);
    u += 0x7fffu + ((u >> 16) & 1u);   // round-to-nearest-even
    return (u16)(u >> 16);
}

__device__ __forceinline__ f32x4 MFMA(u16x8 a, u16x8 b, f32x4 c) {
    return __builtin_amdgcn_mfma_f32_16x16x32_bf16(
        __builtin_bit_cast(short8, a), __builtin_bit_cast(short8, b), c, 0, 0, 0);
}

// convert 8 f32 -> 8 bf16 and store to LDS
__device__ __forceinline__ void store8(u16* dst, const float* src) {
    float4 a = *(const float4*)src;
    float4 b = *(const float4*)(src + 4);
    u16x8 t;
    t[0] = f2bf(a.x); t[1] = f2bf(a.y); t[2] = f2bf(a.z); t[3] = f2bf(a.w);
    t[4] = f2bf(b.x); t[5] = f2bf(b.y); t[6] = f2bf(b.z); t[7] = f2bf(b.w);
    *(u16x8*)dst = t;
}

// GEMM row r (chunk-local, window order: lb*4096 + w*64 + t) -> image-order row.
__device__ __forceinline__ int win2img(int r) {
    int b = r >> 12;
    int w = (r >> 6) & 63;
    int t = r & 63;
    int img = (((w >> 3) << 3) + (t >> 3)) * 64 + ((w & 7) << 3) + (t & 7);
    return (b << 12) + img;
}

// C[M x Nfull] = A[M x 512] @ Wt[Nfull x 512]^T + bias.  M = bc*4096.
// PERM_IN: A rows gathered image-order (window partition).
// PERM_OUT: C rows scattered image-order (window reverse).
// IN_BF16: A is bf16 scratch (else f32). OUT_F32: C is f32 (else bf16 scratch).
template<bool PERM_IN, bool PERM_OUT, bool IN_BF16, bool OUT_F32>
__global__ __launch_bounds__(256, 2)
void gemm_bt(const void* __restrict__ A, const float* __restrict__ Wt,
             const float* __restrict__ bias, void* __restrict__ C, int Nfull)
{
    __shared__ u16 sA[128][40];   // +8 pad: conflict-free b128 frag reads
    __shared__ u16 sB[128][40];

    const int tid  = threadIdx.x;
    const int lane = tid & 63;
    const int wv   = tid >> 6;
    const int wm   = (wv >> 1) << 6;   // wave row offset in tile
    const int wn   = (wv & 1) << 6;    // wave col offset
    const int lr   = lane & 15;
    const int lg   = lane >> 4;
    const int m0   = blockIdx.x * 128;
    const int n0   = blockIdx.y * 128;

    const int sr = tid >> 2;           // staging row 0..63
    const int kq = (tid & 3) << 3;     // staging k element offset 0/8/16/24

    int g0 = m0 + sr, g1 = m0 + 64 + sr;
    if (PERM_IN) { g0 = win2img(g0); g1 = win2img(g1); }

    const u16   *aB0 = nullptr, *aB1 = nullptr;
    const float *aF0 = nullptr, *aF1 = nullptr;
    if constexpr (IN_BF16) {
        aB0 = (const u16*)A + (size_t)g0 * 512 + kq;
        aB1 = (const u16*)A + (size_t)g1 * 512 + kq;
    } else {
        aF0 = (const float*)A + (size_t)g0 * 512 + kq;
        aF1 = (const float*)A + (size_t)g1 * 512 + kq;
    }
    const float* bptr0 = Wt + (size_t)(n0 + sr) * 512 + kq;
    const float* bptr1 = Wt + (size_t)(n0 + 64 + sr) * 512 + kq;

    f32x4 acc[4][4] = {};

    for (int kt = 0; kt < 16; ++kt) {
        __syncthreads();
        if constexpr (IN_BF16) {
            *(u16x8*)&sA[sr][kq]      = *(const u16x8*)(aB0 + kt * 32);
            *(u16x8*)&sA[64 + sr][kq] = *(const u16x8*)(aB1 + kt * 32);
        } else {
            store8(&sA[sr][kq],      aF0 + kt * 32);
            store8(&sA[64 + sr][kq], aF1 + kt * 32);
        }
        store8(&sB[sr][kq],      bptr0 + kt * 32);
        store8(&sB[64 + sr][kq], bptr1 + kt * 32);
        __syncthreads();

        u16x8 af[4], bfr[4];
#pragma unroll
        for (int mi = 0; mi < 4; ++mi)
            af[mi] = *(const u16x8*)&sA[wm + mi * 16 + lr][lg * 8];
#pragma unroll
        for (int ni = 0; ni < 4; ++ni)
            bfr[ni] = *(const u16x8*)&sB[wn + ni * 16 + lr][lg * 8];
#pragma unroll
        for (int mi = 0; mi < 4; ++mi)
#pragma unroll
            for (int ni = 0; ni < 4; ++ni)
                acc[mi][ni] = MFMA(af[mi], bfr[ni], acc[mi][ni]);
    }

#pragma unroll
    for (int mi = 0; mi < 4; ++mi) {
#pragma unroll
        for (int ni = 0; ni < 4; ++ni) {
            const int col = n0 + wn + ni * 16 + lr;
            const float bv = bias[col];
#pragma unroll
            for (int r = 0; r < 4; ++r) {
                int grow = m0 + wm + mi * 16 + lg * 4 + r;
                if (PERM_OUT) grow = win2img(grow);
                const float v = acc[mi][ni][r] + bv;
                if constexpr (OUT_F32)
                    ((float*)C)[(size_t)grow * Nfull + col] = v;
                else
                    ((u16*)C)[(size_t)grow * Nfull + col] = f2bf(v);
            }
        }
    }
}

// Attention: one block per window (64 tokens). 4 waves x 4 heads each.
// qkv: [bc*4096][1536] bf16 (q|k|v each 512 = 16 heads * 32).
// attn_out: [bc*4096][512] bf16.
__global__ __launch_bounds__(256, 2)
void attn_kernel(const u16* __restrict__ qkv, const float* __restrict__ mask,
                 u16* __restrict__ attn_out)
{
    __shared__ u16 sP[4][64][72];   // per-wave P scratch, +8 pad

    const int tid  = threadIdx.x;
    const int lane = tid & 63;
    const int wv   = tid >> 6;
    const int lr   = lane & 15;
    const int lg   = lane >> 4;
    const int win  = blockIdx.x;
    const int wib  = win & 63;                  // window index within batch
    const size_t rb = (size_t)win * 64;         // row base in qkv/attn buffers
    const float* maskp = mask + (size_t)wib * 64 * 64;
    const float scale = 0.17677669529663687f;   // 32^-0.5

    for (int hi = 0; hi < 4; ++hi) {
        const int h = hi * 4 + wv;
        const size_t hoff = (size_t)h * 32;

        // ---- S = Q K^T ----
        u16x8 qf[4], kf[4];
#pragma unroll
        for (int mt = 0; mt < 4; ++mt) {
            const u16* rowp = qkv + (rb + mt * 16 + lr) * 1536 + hoff + lg * 8;
            qf[mt] = *(const u16x8*)rowp;
            kf[mt] = *(const u16x8*)(rowp + 512);
        }
        f32x4 s[4][4] = {};
#pragma unroll
        for (int mi = 0; mi < 4; ++mi)
#pragma unroll
            for (int ni = 0; ni < 4; ++ni)
                s[mi][ni] = MFMA(qf[mi], kf[ni], s[mi][ni]);

        // ---- scale + mask + softmax (rows live in 16-lane groups) ----
        float rsum[4][4];
#pragma unroll
        for (int mi = 0; mi < 4; ++mi) {
#pragma unroll
            for (int r = 0; r < 4; ++r) {
                const int qrow = mi * 16 + lg * 4 + r;
                float vv[4];
                float mx = -1e30f;
#pragma unroll
                for (int ni = 0; ni < 4; ++ni) {
                    const int kcol = ni * 16 + lr;
                    float v = s[mi][ni][r] * scale + maskp[qrow * 64 + kcol];
                    vv[ni] = v;
                    mx = fmaxf(mx, v);
                }
#pragma unroll
                for (int mk = 1; mk <= 8; mk <<= 1)
                    mx = fmaxf(mx, __shfl_xor(mx, mk, 64));
                float sum = 0.f;
#pragma unroll
                for (int ni = 0; ni < 4; ++ni) {
                    float p = __expf(vv[ni] - mx);
                    sum += p;
                    s[mi][ni][r] = p;
                }
#pragma unroll
                for (int mk = 1; mk <= 8; mk <<= 1)
                    sum += __shfl_xor(sum, mk, 64);
                rsum[mi][r] = sum;
            }
        }

        __syncthreads();
#pragma unroll
        for (int mi = 0; mi < 4; ++mi)
#pragma unroll
            for (int ni = 0; ni < 4; ++ni)
#pragma unroll
                for (int r = 0; r < 4; ++r)
                    sP[wv][mi * 16 + lg * 4 + r][ni * 16 + lr] = f2bf(s[mi][ni][r]);
        __syncthreads();

        // ---- O = P V ----
        u16x8 pf[4][2];
#pragma unroll
        for (int mt = 0; mt < 4; ++mt)
#pragma unroll
            for (int k2 = 0; k2 < 2; ++k2)
                pf[mt][k2] = *(const u16x8*)&sP[wv][mt * 16 + lr][k2 * 32 + lg * 8];

        u16x8 vf[2][2];
#pragma unroll
        for (int k2 = 0; k2 < 2; ++k2)
#pragma unroll
            for (int nt = 0; nt < 2; ++nt) {
                const u16* vp = qkv + (rb + k2 * 32 + lg * 8) * 1536 + 1024 + hoff + nt * 16 + lr;
                u16x8 tmp;
#pragma unroll
                for (int j = 0; j < 8; ++j) tmp[j] = vp[(size_t)j * 1536];
                vf[k2][nt] = tmp;
            }

        f32x4 o[4][2] = {};
#pragma unroll
        for (int mt = 0; mt < 4; ++mt)
#pragma unroll
            for (int k2 = 0; k2 < 2; ++k2)
#pragma unroll
                for (int nt = 0; nt < 2; ++nt)
                    o[mt][nt] = MFMA(pf[mt][k2], vf[k2][nt], o[mt][nt]);

#pragma unroll
        for (int mt = 0; mt < 4; ++mt)
#pragma unroll
            for (int nt = 0; nt < 2; ++nt)
#pragma unroll
                for (int r = 0; r < 4; ++r) {
                    const int row = mt * 16 + lg * 4 + r;
                    const int d = nt * 16 + lr;
                    attn_out[(rb + row) * 512 + hoff + d] =
                        f2bf(o[mt][nt][r] / rsum[mt][r]);
                }
    }
}

extern "C" void kernel_launch(void* const* d_in, const int* in_sizes, int n_in,
                              void* d_out, int out_size, void* d_ws, size_t ws_size,
                              hipStream_t stream)
{
    const float* x      = (const float*)d_in[0];
    const float* qkv_w  = (const float*)d_in[1];
    const float* qkv_b  = (const float*)d_in[2];
    const float* proj_w = (const float*)d_in[3];
    const float* proj_b = (const float*)d_in[4];
    const float* mask   = (const float*)d_in[5];
    float* out = (float*)d_out;

    const size_t qkvPB = 4096ull * 1536;   // bf16 elements per batch, qkv buffer
    const size_t attPB = 4096ull * 512;    // bf16 elements per batch, attn buffer
    const size_t perBatchBytes = (qkvPB + attPB) * 2;

    int Bc = (int)(ws_size / perBatchBytes);
    if (Bc > 16) Bc = 16;
    if (Bc < 1) Bc = 1;

    u16* qkv_ws = (u16*)d_ws;
    u16* att_ws = qkv_ws + (size_t)Bc * qkvPB;

    for (int b0 = 0; b0 < 16; b0 += Bc) {
        const int bc = (16 - b0) < Bc ? (16 - b0) : Bc;
        const float* xc = x + (size_t)b0 * 4096 * 512;
        float* outc = out + (size_t)b0 * 4096 * 512;

        gemm_bt<true, false, false, false><<<dim3(bc * 32, 12), 256, 0, stream>>>(
            xc, qkv_w, qkv_b, qkv_ws, 1536);
        attn_kernel<<<dim3(bc * 64), 256, 0, stream>>>(qkv_ws, mask, att_ws);
        gemm_bt<false, true, true, true><<<dim3(bc * 32, 4), 256, 0, stream>>>(
            att_ws, proj_w, proj_b, outc, 512);
    }
}

// Round 3
// 349.002 us; speedup vs baseline: 1.3453x; 1.3453x over previous
//
#include <hip/hip_runtime.h>

// Window MHA: B=16, H=W=64, C=512, WS=8, NH=16, hd=32.
// f32 I/O. Pipeline: convert(weights) once; per chunk:
//   conv_permute_x (f32->bf16 + window partition) ->
//   QKV GEMM (m97-style global_load_lds) -> attn -> proj GEMM (f32 out + reverse).

typedef unsigned short u16;
typedef unsigned int u32;
typedef __attribute__((ext_vector_type(8))) u16 u16x8;
typedef __attribute__((ext_vector_type(8))) short short8;
typedef __attribute__((ext_vector_type(4))) float f32x4;

__device__ __forceinline__ u16 f2bf(float f) {
    u32 u = __float_as_uint(f);
    u += 0x7fffu + ((u >> 16) & 1u);   // RNE
    return (u16)(u >> 16);
}

__device__ __forceinline__ f32x4 MFMA(u16x8 a, u16x8 b, f32x4 c) {
    return __builtin_amdgcn_mfma_f32_16x16x32_bf16(
        __builtin_bit_cast(short8, a), __builtin_bit_cast(short8, b), c, 0, 0, 0);
}

__device__ __forceinline__ void gload16(const void* g, void* l) {
    __builtin_amdgcn_global_load_lds(
        (const __attribute__((address_space(1))) void*)g,
        (__attribute__((address_space(3))) void*)l, 16, 0, 0);
}

// chunk-local window-order row -> image-order row
__device__ __forceinline__ int win2img(int r) {
    int b = r >> 12;
    int w = (r >> 6) & 63;
    int t = r & 63;
    int img = (((w >> 3) << 3) + (t >> 3)) * 64 + ((w & 7) << 3) + (t & 7);
    return (b << 12) + img;
}

__device__ __forceinline__ u16x8 cvt8(const float* src) {
    float4 a = *(const float4*)src;
    float4 b = *(const float4*)(src + 4);
    u16x8 t;
    t[0] = f2bf(a.x); t[1] = f2bf(a.y); t[2] = f2bf(a.z); t[3] = f2bf(a.w);
    t[4] = f2bf(b.x); t[5] = f2bf(b.y); t[6] = f2bf(b.z); t[7] = f2bf(b.w);
    return t;
}

// f32 -> bf16 plain convert (weights). n8 = elems/8.
__global__ __launch_bounds__(256)
void conv_f2b(const float* __restrict__ in, u16* __restrict__ out, int n8) {
    int u = blockIdx.x * 256 + threadIdx.x;
    if (u >= n8) return;
    *(u16x8*)(out + (size_t)u * 8) = cvt8(in + (size_t)u * 8);
}

// x (f32, image order) -> xw (bf16, window order). One wave handles one row.
__global__ __launch_bounds__(256)
void conv_permute_x(const float* __restrict__ x, u16* __restrict__ xw) {
    int u = blockIdx.x * 256 + threadIdx.x;   // unit = 8 elems
    int r = u >> 6;                           // window-order row
    int c = (u & 63) << 3;
    int g = win2img(r);
    *(u16x8*)(xw + (size_t)r * 512 + c) = cvt8(x + (size_t)g * 512 + c);
}

// C[M x Nfull] = A[M x 512]bf16 @ Wt[Nfull x 512]bf16^T + bias(f32).
// m97 structure: 128x128 tile, BK=32, linear LDS, global_load_lds 16B staging.
template<bool PERM_OUT, bool OUT_F32>
__global__ __launch_bounds__(256, 2)
void gemm_bt(const u16* __restrict__ A, const u16* __restrict__ Wt,
             const float* __restrict__ bias, void* __restrict__ C, int Nfull)
{
    __shared__ u16 sA[128 * 32];   // linear: row*32 + k  (gload_lds order)
    __shared__ u16 sB[128 * 32];

    const int tid  = threadIdx.x;
    const int lane = tid & 63;
    const int wv   = tid >> 6;
    const int wm   = (wv >> 1) << 6;
    const int wn   = (wv & 1) << 6;
    const int lr   = lane & 15;
    const int lg   = lane >> 4;
    const int m0   = blockIdx.x * 128;
    const int n0   = blockIdx.y * 128;

    // staging slice: thread t covers LDS bytes [t*16, t*16+16) of each 4KB half
    const int grow  = tid >> 2;          // 0..63
    const int gcolb = (tid & 3) << 4;    // byte offset within 64B k-row
    const u32 tb    = (u32)tid * 16;

    const char* aptr = (const char*)A + (((size_t)(m0 + grow)) << 10) + gcolb;
    const char* bptr = (const char*)Wt + (((size_t)(n0 + grow)) << 10) + gcolb;
    char* sAb = (char*)sA;
    char* sBb = (char*)sB;

    f32x4 acc[4][4] = {};

    for (int kt = 0; kt < 16; ++kt) {
        __syncthreads();                      // previous frag reads done
        const int ko = kt * 64;               // byte offset along K
        gload16(aptr + ko,              sAb + tb);
        gload16(aptr + (64 << 10) + ko, sAb + 4096 + tb);
        gload16(bptr + ko,              sBb + tb);
        gload16(bptr + (64 << 10) + ko, sBb + 4096 + tb);
        __syncthreads();                      // drains vmcnt before barrier

        u16x8 af[4], bfr[4];
#pragma unroll
        for (int mi = 0; mi < 4; ++mi)
            af[mi] = *(const u16x8*)(sA + (wm + mi * 16 + lr) * 32 + lg * 8);
#pragma unroll
        for (int ni = 0; ni < 4; ++ni)
            bfr[ni] = *(const u16x8*)(sB + (wn + ni * 16 + lr) * 32 + lg * 8);
#pragma unroll
        for (int mi = 0; mi < 4; ++mi)
#pragma unroll
            for (int ni = 0; ni < 4; ++ni)
                acc[mi][ni] = MFMA(af[mi], bfr[ni], acc[mi][ni]);
    }

#pragma unroll
    for (int mi = 0; mi < 4; ++mi) {
#pragma unroll
        for (int ni = 0; ni < 4; ++ni) {
            const int col = n0 + wn + ni * 16 + lr;
            const float bv = bias[col];
#pragma unroll
            for (int r = 0; r < 4; ++r) {
                int gr = m0 + wm + mi * 16 + lg * 4 + r;
                if (PERM_OUT) gr = win2img(gr);
                const float v = acc[mi][ni][r] + bv;
                if constexpr (OUT_F32)
                    ((float*)C)[(size_t)gr * Nfull + col] = v;
                else
                    ((u16*)C)[(size_t)gr * Nfull + col] = f2bf(v);
            }
        }
    }
}

// Attention: one block per window (64 tokens). 4 waves x 4 heads each.
// qkv: [rows][1536] bf16 (q|k|v each 512). attn_out: [rows][512] bf16.
__global__ __launch_bounds__(256, 2)
void attn_kernel(const u16* __restrict__ qkv, const float* __restrict__ mask,
                 u16* __restrict__ attn_out)
{
    __shared__ u16 sP[4][64][72];

    const int tid  = threadIdx.x;
    const int lane = tid & 63;
    const int wv   = tid >> 6;
    const int lr   = lane & 15;
    const int lg   = lane >> 4;
    const int win  = blockIdx.x;
    const int wib  = win & 63;
    const size_t rb = (size_t)win * 64;
    const float* maskp = mask + (size_t)wib * 64 * 64;
    const float scale = 0.17677669529663687f;   // 32^-0.5

    for (int hi = 0; hi < 4; ++hi) {
        const int h = hi * 4 + wv;
        const size_t hoff = (size_t)h * 32;

        // ---- S = Q K^T ----
        u16x8 qf[4], kf[4];
#pragma unroll
        for (int mt = 0; mt < 4; ++mt) {
            const u16* rowp = qkv + (rb + mt * 16 + lr) * 1536 + hoff + lg * 8;
            qf[mt] = *(const u16x8*)rowp;
            kf[mt] = *(const u16x8*)(rowp + 512);
        }
        f32x4 s[4][4] = {};
#pragma unroll
        for (int mi = 0; mi < 4; ++mi)
#pragma unroll
            for (int ni = 0; ni < 4; ++ni)
                s[mi][ni] = MFMA(qf[mi], kf[ni], s[mi][ni]);

        // ---- scale + mask + softmax ----
        float rsum[4][4];
#pragma unroll
        for (int mi = 0; mi < 4; ++mi) {
#pragma unroll
            for (int r = 0; r < 4; ++r) {
                const int qrow = mi * 16 + lg * 4 + r;
                float vv[4];
                float mx = -1e30f;
#pragma unroll
                for (int ni = 0; ni < 4; ++ni) {
                    const int kcol = ni * 16 + lr;
                    float v = s[mi][ni][r] * scale + maskp[qrow * 64 + kcol];
                    vv[ni] = v;
                    mx = fmaxf(mx, v);
                }
#pragma unroll
                for (int mk = 1; mk <= 8; mk <<= 1)
                    mx = fmaxf(mx, __shfl_xor(mx, mk, 64));
                float sum = 0.f;
#pragma unroll
                for (int ni = 0; ni < 4; ++ni) {
                    float p = __expf(vv[ni] - mx);
                    sum += p;
                    s[mi][ni][r] = p;
                }
#pragma unroll
                for (int mk = 1; mk <= 8; mk <<= 1)
                    sum += __shfl_xor(sum, mk, 64);
                rsum[mi][r] = sum;
            }
        }

        __syncthreads();
#pragma unroll
        for (int mi = 0; mi < 4; ++mi)
#pragma unroll
            for (int ni = 0; ni < 4; ++ni)
#pragma unroll
                for (int r = 0; r < 4; ++r)
                    sP[wv][mi * 16 + lg * 4 + r][ni * 16 + lr] = f2bf(s[mi][ni][r]);
        __syncthreads();

        // ---- O = P V ----
        u16x8 pf[4][2];
#pragma unroll
        for (int mt = 0; mt < 4; ++mt)
#pragma unroll
            for (int k2 = 0; k2 < 2; ++k2)
                pf[mt][k2] = *(const u16x8*)&sP[wv][mt * 16 + lr][k2 * 32 + lg * 8];

        u16x8 vf[2][2];
#pragma unroll
        for (int k2 = 0; k2 < 2; ++k2)
#pragma unroll
            for (int nt = 0; nt < 2; ++nt) {
                const u16* vp = qkv + (rb + k2 * 32 + lg * 8) * 1536 + 1024 + hoff + nt * 16 + lr;
                u16x8 tmp;
#pragma unroll
                for (int j = 0; j < 8; ++j) tmp[j] = vp[(size_t)j * 1536];
                vf[k2][nt] = tmp;
            }

        f32x4 o[4][2] = {};
#pragma unroll
        for (int mt = 0; mt < 4; ++mt)
#pragma unroll
            for (int k2 = 0; k2 < 2; ++k2)
#pragma unroll
                for (int nt = 0; nt < 2; ++nt)
                    o[mt][nt] = MFMA(pf[mt][k2], vf[k2][nt], o[mt][nt]);

#pragma unroll
        for (int mt = 0; mt < 4; ++mt)
#pragma unroll
            for (int nt = 0; nt < 2; ++nt)
#pragma unroll
                for (int r = 0; r < 4; ++r) {
                    const int row = mt * 16 + lg * 4 + r;
                    const int d = nt * 16 + lr;
                    attn_out[(rb + row) * 512 + hoff + d] =
                        f2bf(o[mt][nt][r] / rsum[mt][r]);
                }
    }
}

extern "C" void kernel_launch(void* const* d_in, const int* in_sizes, int n_in,
                              void* d_out, int out_size, void* d_ws, size_t ws_size,
                              hipStream_t stream)
{
    const float* x      = (const float*)d_in[0];
    const float* qkv_w  = (const float*)d_in[1];
    const float* qkv_b  = (const float*)d_in[2];
    const float* proj_w = (const float*)d_in[3];
    const float* proj_b = (const float*)d_in[4];
    const float* mask   = (const float*)d_in[5];
    float* out = (float*)d_out;

    const size_t WQKV = 1536ull * 512;   // qkv_w elems
    const size_t WPROJ = 512ull * 512;   // proj_w elems

    u16* wq = (u16*)d_ws;
    u16* wp = wq + WQKV;
    u16* chunk = wp + WPROJ;

    const size_t xwPB  = 4096ull * 512;    // per-batch elems
    const size_t qkvPB = 4096ull * 1536;
    const size_t attPB = 4096ull * 512;
    const size_t perBatchBytes = (xwPB + qkvPB + attPB) * 2;

    size_t avail = ws_size - (WQKV + WPROJ) * 2;
    int Bc = (int)(avail / perBatchBytes);
    if (Bc > 16) Bc = 16;
    if (Bc < 1) Bc = 1;

    u16* xw_ws  = chunk;
    u16* qkv_ws = xw_ws + (size_t)Bc * xwPB;
    u16* att_ws = qkv_ws + (size_t)Bc * qkvPB;

    conv_f2b<<<dim3((WQKV / 8 + 255) / 256), 256, 0, stream>>>(qkv_w, wq, (int)(WQKV / 8));
    conv_f2b<<<dim3((WPROJ / 8 + 255) / 256), 256, 0, stream>>>(proj_w, wp, (int)(WPROJ / 8));

    for (int b0 = 0; b0 < 16; b0 += Bc) {
        const int bc = (16 - b0) < Bc ? (16 - b0) : Bc;
        const float* xc = x + (size_t)b0 * 4096 * 512;
        float* outc = out + (size_t)b0 * 4096 * 512;

        conv_permute_x<<<dim3(bc * 1024), 256, 0, stream>>>(xc, xw_ws);
        gemm_bt<false, false><<<dim3(bc * 32, 12), 256, 0, stream>>>(
            xw_ws, wq, qkv_b, qkv_ws, 1536);
        attn_kernel<<<dim3(bc * 64), 256, 0, stream>>>(qkv_ws, mask, att_ws);
        gemm_bt<true, true><<<dim3(bc * 32, 4), 256, 0, stream>>>(
            att_ws, wp, proj_b, outc, 512);
    }
}

// Round 4
// 332.020 us; speedup vs baseline: 1.4141x; 1.0511x over previous
//
#include <hip/hip_runtime.h>

// Window MHA: B=16, H=W=64, C=512, WS=8, NH=16, hd=32. f32 I/O.
// Pipeline per chunk: conv_permute_x (f32->bf16 + window partition) ->
// QKV GEMM -> attn -> proj GEMM (f32 out + window reverse).
// GEMMs: 128x128 tile, BK=32, 2-phase LDS double-buffer with early
// global_load_lds issue (T3-min), N-fastest grid + bijective XCD swizzle (T1).

typedef unsigned short u16;
typedef unsigned int u32;
typedef __attribute__((ext_vector_type(8))) u16 u16x8;
typedef __attribute__((ext_vector_type(8))) short short8;
typedef __attribute__((ext_vector_type(4))) float f32x4;

__device__ __forceinline__ u16 f2bf(float f) {
    u32 u = __float_as_uint(f);
    u += 0x7fffu + ((u >> 16) & 1u);   // RNE
    return (u16)(u >> 16);
}

__device__ __forceinline__ f32x4 MFMA(u16x8 a, u16x8 b, f32x4 c) {
    return __builtin_amdgcn_mfma_f32_16x16x32_bf16(
        __builtin_bit_cast(short8, a), __builtin_bit_cast(short8, b), c, 0, 0, 0);
}

__device__ __forceinline__ void gload16(const void* g, void* l) {
    __builtin_amdgcn_global_load_lds(
        (const __attribute__((address_space(1))) void*)g,
        (__attribute__((address_space(3))) void*)l, 16, 0, 0);
}

// chunk-local window-order row -> image-order row
__device__ __forceinline__ int win2img(int r) {
    int b = r >> 12;
    int w = (r >> 6) & 63;
    int t = r & 63;
    int img = (((w >> 3) << 3) + (t >> 3)) * 64 + ((w & 7) << 3) + (t & 7);
    return (b << 12) + img;
}

__device__ __forceinline__ u16x8 cvt8(const float* src) {
    float4 a = *(const float4*)src;
    float4 b = *(const float4*)(src + 4);
    u16x8 t;
    t[0] = f2bf(a.x); t[1] = f2bf(a.y); t[2] = f2bf(a.z); t[3] = f2bf(a.w);
    t[4] = f2bf(b.x); t[5] = f2bf(b.y); t[6] = f2bf(b.z); t[7] = f2bf(b.w);
    return t;
}

// f32 -> bf16 plain convert (weights). n8 = elems/8.
__global__ __launch_bounds__(256)
void conv_f2b(const float* __restrict__ in, u16* __restrict__ out, int n8) {
    int u = blockIdx.x * 256 + threadIdx.x;
    if (u >= n8) return;
    *(u16x8*)(out + (size_t)u * 8) = cvt8(in + (size_t)u * 8);
}

// x (f32, image order) -> xw (bf16, window order).
__global__ __launch_bounds__(256)
void conv_permute_x(const float* __restrict__ x, u16* __restrict__ xw) {
    int u = blockIdx.x * 256 + threadIdx.x;   // unit = 8 elems
    int r = u >> 6;                           // window-order row
    int c = (u & 63) << 3;
    int g = win2img(r);
    *(u16x8*)(xw + (size_t)r * 512 + c) = cvt8(x + (size_t)g * 512 + c);
}

// C[M x Nfull] = A[M x 512]bf16 @ Wt[Nfull x 512]bf16^T + bias(f32).
// grid: 1-D, nwg = MB*NB (multiple of 8). Decode: XCD-swizzle then N-fastest.
template<bool PERM_OUT, bool OUT_F32>
__global__ __launch_bounds__(256, 4)
void gemm_bt(const u16* __restrict__ A, const u16* __restrict__ Wt,
             const float* __restrict__ bias, void* __restrict__ C,
             int NB, int Nfull)
{
    __shared__ char lds[32768];   // [buf:2][A 8KB | B 8KB]

    const int nwg = gridDim.x;            // % 8 == 0
    const int q   = nwg >> 3;
    const int wg  = (blockIdx.x & 7) * q + (blockIdx.x >> 3);
    const int m0  = (wg / NB) * 128;
    const int n0  = (wg % NB) * 128;

    const int tid  = threadIdx.x;
    const int lane = tid & 63;
    const int wv   = tid >> 6;
    const int wm   = (wv >> 1) << 6;
    const int wn   = (wv & 1) << 6;
    const int lr   = lane & 15;
    const int lg   = lane >> 4;

    // staging: thread t covers LDS bytes [t*16, t*16+16) of each 4KB half
    const int grow  = tid >> 2;           // 0..63
    const int gcolb = (tid & 3) << 4;     // byte offset within 64B k-row
    const u32 tb    = (u32)tid << 4;

    const char* aptr = (const char*)A + (((size_t)(m0 + grow)) << 10) + gcolb;
    const char* bptr = (const char*)Wt + (((size_t)(n0 + grow)) << 10) + gcolb;

    f32x4 acc[4][4] = {};

#define STAGE(buf, kt) do {                                                   \
    const int ko_ = (kt) * 64;                                                \
    char* d_ = lds + (buf) * 16384 + tb;                                      \
    gload16(aptr + ko_,              d_);                                     \
    gload16(aptr + (64 << 10) + ko_, d_ + 4096);                              \
    gload16(bptr + ko_,              d_ + 8192);                              \
    gload16(bptr + (64 << 10) + ko_, d_ + 12288);                             \
} while (0)

#define COMPUTE(buf) do {                                                     \
    const u16* As_ = (const u16*)(lds + (buf) * 16384);                       \
    const u16* Bs_ = (const u16*)(lds + (buf) * 16384 + 8192);                \
    u16x8 af_[4], bf_[4];                                                     \
    _Pragma("unroll")                                                         \
    for (int mi = 0; mi < 4; ++mi)                                            \
        af_[mi] = *(const u16x8*)(As_ + (wm + mi * 16 + lr) * 32 + lg * 8);   \
    _Pragma("unroll")                                                         \
    for (int ni = 0; ni < 4; ++ni)                                            \
        bf_[ni] = *(const u16x8*)(Bs_ + (wn + ni * 16 + lr) * 32 + lg * 8);   \
    _Pragma("unroll")                                                         \
    for (int mi = 0; mi < 4; ++mi)                                            \
        _Pragma("unroll")                                                     \
        for (int ni = 0; ni < 4; ++ni)                                        \
            acc[mi][ni] = MFMA(af_[mi], bf_[ni], acc[mi][ni]);                \
} while (0)

    STAGE(0, 0);
    __syncthreads();

#pragma unroll 1
    for (int kt = 0; kt < 16; kt += 2) {
        STAGE(1, kt + 1);          // issue next-tile loads, fly during compute
        COMPUTE(0);
        __syncthreads();           // drains vmcnt(0): buf1 ready
        if (kt + 2 < 16) STAGE(0, kt + 2);
        COMPUTE(1);
        __syncthreads();
    }

#undef STAGE
#undef COMPUTE

#pragma unroll
    for (int mi = 0; mi < 4; ++mi) {
#pragma unroll
        for (int ni = 0; ni < 4; ++ni) {
            const int col = n0 + wn + ni * 16 + lr;
            const float bv = bias[col];
#pragma unroll
            for (int r = 0; r < 4; ++r) {
                int gr = m0 + wm + mi * 16 + lg * 4 + r;
                if (PERM_OUT) gr = win2img(gr);
                const float v = acc[mi][ni][r] + bv;
                if constexpr (OUT_F32)
                    ((float*)C)[(size_t)gr * Nfull + col] = v;
                else
                    ((u16*)C)[(size_t)gr * Nfull + col] = f2bf(v);
            }
        }
    }
}

// Attention: one block per window (64 tokens). 4 waves x 4 heads each.
__global__ __launch_bounds__(256, 2)
void attn_kernel(const u16* __restrict__ qkv, const float* __restrict__ mask,
                 u16* __restrict__ attn_out)
{
    __shared__ u16 sP[4][64][72];

    const int tid  = threadIdx.x;
    const int lane = tid & 63;
    const int wv   = tid >> 6;
    const int lr   = lane & 15;
    const int lg   = lane >> 4;
    const int win  = blockIdx.x;
    const int wib  = win & 63;
    const size_t rb = (size_t)win * 64;
    const float* maskp = mask + (size_t)wib * 64 * 64;
    const float scale = 0.17677669529663687f;   // 32^-0.5

    for (int hi = 0; hi < 4; ++hi) {
        const int h = hi * 4 + wv;
        const size_t hoff = (size_t)h * 32;

        u16x8 qf[4], kf[4];
#pragma unroll
        for (int mt = 0; mt < 4; ++mt) {
            const u16* rowp = qkv + (rb + mt * 16 + lr) * 1536 + hoff + lg * 8;
            qf[mt] = *(const u16x8*)rowp;
            kf[mt] = *(const u16x8*)(rowp + 512);
        }
        f32x4 s[4][4] = {};
#pragma unroll
        for (int mi = 0; mi < 4; ++mi)
#pragma unroll
            for (int ni = 0; ni < 4; ++ni)
                s[mi][ni] = MFMA(qf[mi], kf[ni], s[mi][ni]);

        float rsum[4][4];
#pragma unroll
        for (int mi = 0; mi < 4; ++mi) {
#pragma unroll
            for (int r = 0; r < 4; ++r) {
                const int qrow = mi * 16 + lg * 4 + r;
                float vv[4];
                float mx = -1e30f;
#pragma unroll
                for (int ni = 0; ni < 4; ++ni) {
                    const int kcol = ni * 16 + lr;
                    float v = s[mi][ni][r] * scale + maskp[qrow * 64 + kcol];
                    vv[ni] = v;
                    mx = fmaxf(mx, v);
                }
#pragma unroll
                for (int mk = 1; mk <= 8; mk <<= 1)
                    mx = fmaxf(mx, __shfl_xor(mx, mk, 64));
                float sum = 0.f;
#pragma unroll
                for (int ni = 0; ni < 4; ++ni) {
                    float p = __expf(vv[ni] - mx);
                    sum += p;
                    s[mi][ni][r] = p;
                }
#pragma unroll
                for (int mk = 1; mk <= 8; mk <<= 1)
                    sum += __shfl_xor(sum, mk, 64);
                rsum[mi][r] = sum;
            }
        }

        __syncthreads();
#pragma unroll
        for (int mi = 0; mi < 4; ++mi)
#pragma unroll
            for (int ni = 0; ni < 4; ++ni)
#pragma unroll
                for (int r = 0; r < 4; ++r)
                    sP[wv][mi * 16 + lg * 4 + r][ni * 16 + lr] = f2bf(s[mi][ni][r]);
        __syncthreads();

        u16x8 pf[4][2];
#pragma unroll
        for (int mt = 0; mt < 4; ++mt)
#pragma unroll
            for (int k2 = 0; k2 < 2; ++k2)
                pf[mt][k2] = *(const u16x8*)&sP[wv][mt * 16 + lr][k2 * 32 + lg * 8];

        u16x8 vf[2][2];
#pragma unroll
        for (int k2 = 0; k2 < 2; ++k2)
#pragma unroll
            for (int nt = 0; nt < 2; ++nt) {
                const u16* vp = qkv + (rb + k2 * 32 + lg * 8) * 1536 + 1024 + hoff + nt * 16 + lr;
                u16x8 tmp;
#pragma unroll
                for (int j = 0; j < 8; ++j) tmp[j] = vp[(size_t)j * 1536];
                vf[k2][nt] = tmp;
            }

        f32x4 o[4][2] = {};
#pragma unroll
        for (int mt = 0; mt < 4; ++mt)
#pragma unroll
            for (int k2 = 0; k2 < 2; ++k2)
#pragma unroll
                for (int nt = 0; nt < 2; ++nt)
                    o[mt][nt] = MFMA(pf[mt][k2], vf[k2][nt], o[mt][nt]);

#pragma unroll
        for (int mt = 0; mt < 4; ++mt)
#pragma unroll
            for (int nt = 0; nt < 2; ++nt)
#pragma unroll
                for (int r = 0; r < 4; ++r) {
                    const int row = mt * 16 + lg * 4 + r;
                    const int d = nt * 16 + lr;
                    attn_out[(rb + row) * 512 + hoff + d] =
                        f2bf(o[mt][nt][r] / rsum[mt][r]);
                }
    }
}

extern "C" void kernel_launch(void* const* d_in, const int* in_sizes, int n_in,
                              void* d_out, int out_size, void* d_ws, size_t ws_size,
                              hipStream_t stream)
{
    const float* x      = (const float*)d_in[0];
    const float* qkv_w  = (const float*)d_in[1];
    const float* qkv_b  = (const float*)d_in[2];
    const float* proj_w = (const float*)d_in[3];
    const float* proj_b = (const float*)d_in[4];
    const float* mask   = (const float*)d_in[5];
    float* out = (float*)d_out;

    const size_t WQKV  = 1536ull * 512;
    const size_t WPROJ = 512ull * 512;

    u16* wq = (u16*)d_ws;
    u16* wp = wq + WQKV;
    u16* chunk = wp + WPROJ;

    const size_t xwPB  = 4096ull * 512;
    const size_t qkvPB = 4096ull * 1536;
    const size_t attPB = 4096ull * 512;
    const size_t perBatchBytes = (xwPB + qkvPB + attPB) * 2;

    size_t avail = ws_size - (WQKV + WPROJ) * 2;
    int Bc = (int)(avail / perBatchBytes);
    if (Bc > 16) Bc = 16;
    if (Bc < 1) Bc = 1;

    u16* xw_ws  = chunk;
    u16* qkv_ws = xw_ws + (size_t)Bc * xwPB;
    u16* att_ws = qkv_ws + (size_t)Bc * qkvPB;

    conv_f2b<<<dim3((WQKV / 8 + 255) / 256), 256, 0, stream>>>(qkv_w, wq, (int)(WQKV / 8));
    conv_f2b<<<dim3((WPROJ / 8 + 255) / 256), 256, 0, stream>>>(proj_w, wp, (int)(WPROJ / 8));

    for (int b0 = 0; b0 < 16; b0 += Bc) {
        const int bc = (16 - b0) < Bc ? (16 - b0) : Bc;
        const float* xc = x + (size_t)b0 * 4096 * 512;
        float* outc = out + (size_t)b0 * 4096 * 512;

        conv_permute_x<<<dim3(bc * 1024), 256, 0, stream>>>(xc, xw_ws);
        // nwg = bc*32*12 (mult of 8): N-fastest decode inside kernel
        gemm_bt<false, false><<<dim3(bc * 32 * 12), 256, 0, stream>>>(
            xw_ws, wq, qkv_b, qkv_ws, 12, 1536);
        attn_kernel<<<dim3(bc * 64), 256, 0, stream>>>(qkv_ws, mask, att_ws);
        gemm_bt<true, true><<<dim3(bc * 32 * 4), 256, 0, stream>>>(
            att_ws, wp, proj_b, outc, 4, 512);
    }
}